// Round 10
// baseline (276.265 us; speedup 1.0000x reference)
//
#include <hip/hip_runtime.h>
#include <hip/hip_bf16.h>
#include <stdint.h>

// LightAttention: out = x + gamma * softmax((x Wq^T)(x Wk^T)^T / sqrt(D)) @ x
// B=4, T=4096, D=512, fp32 in/out.
// R10: attack LDS (measured dominant pipe): 2x32q QK waves (halve K re-read),
// reg-staged K with 8B-granular XOR swizzle (conflict-free per quarter-wave),
// P stride 136 (conflict-free P reads). fp8 pipeline as R8/R9.

#define B_ 4
#define T_ 4096
#define D_ 512

typedef short short8 __attribute__((ext_vector_type(8)));   // 8 bf16 in 4 VGPRs
typedef float f32x4 __attribute__((ext_vector_type(4)));

__device__ __forceinline__ unsigned short f2bf(float x) {
  union { float f; unsigned u; } v; v.f = x;
  unsigned r = v.u + 0x7fffu + ((v.u >> 16) & 1u);   // RNE
  return (unsigned short)(r >> 16);
}
__device__ __forceinline__ unsigned char f2fp8(float x) {
  return (unsigned char)(__builtin_amdgcn_cvt_pk_fp8_f32(x, x, 0, false) & 0xff);
}
__device__ __forceinline__ float bf2f(unsigned short b) {
  union { unsigned u; float f; } v; v.u = ((unsigned)b) << 16; return v.f;
}

__device__ __forceinline__ void gload_lds16(const void* g, void* l) {
  __builtin_amdgcn_global_load_lds((const __attribute__((address_space(1))) void*)g,
                                   (__attribute__((address_space(3))) void*)l, 16, 0, 0);
}

// ---------------- kernel 1: Wq/Wk fp32 -> bf16 ----------------
__global__ __launch_bounds__(256) void cvt_w(const float* __restrict__ wq,
                                             const float* __restrict__ wk,
                                             unsigned short* __restrict__ oq,
                                             unsigned short* __restrict__ ok) {
  int i = (blockIdx.x * 256 + threadIdx.x) * 4;
  const float* s; unsigned short* d;
  if (i < 262144) { s = wq + i; d = oq + i; }
  else            { s = wk + (i - 262144); d = ok + (i - 262144); }
  float4 v = *(const float4*)s;
  ushort4 h; h.x = f2bf(v.x); h.y = f2bf(v.y); h.z = f2bf(v.z); h.w = f2bf(v.w);
  *(ushort4*)d = h;
}

// ---------------- kernel 2: x -> xb (bf16 row-major) + xV (fp8, tile-contig) --------
// xV layout: [b][tile(64kv)][d(512)][64 t-in-tile] fp8.
__global__ __launch_bounds__(256) void prep_x(const float* __restrict__ x,
                                              unsigned short* __restrict__ xb,
                                              unsigned char* __restrict__ xV) {
  __shared__ unsigned short ldsT[64][72];
  int wg = blockIdx.x;                 // 2048 = 4 * (4096/64) * (512/64)
  int b = wg >> 9;
  int rem = wg & 511;
  int tt = rem >> 3, dt = rem & 7;
  int t0 = tt * 64, d0 = dt * 64;
  int tid = threadIdx.x;
  int p = tid & 15, rw = tid >> 4;
#pragma unroll
  for (int k = 0; k < 4; ++k) {
    int tr = rw + 16 * k;
    size_t off = ((size_t)(b * 4096 + t0 + tr)) * 512 + d0 + p * 4;
    float4 v = *(const float4*)(x + off);
    ushort4 h; h.x = f2bf(v.x); h.y = f2bf(v.y); h.z = f2bf(v.z); h.w = f2bf(v.w);
    *(ushort4*)(xb + off) = h;
    ldsT[p * 4 + 0][tr] = h.x; ldsT[p * 4 + 1][tr] = h.y;
    ldsT[p * 4 + 2][tr] = h.z; ldsT[p * 4 + 3][tr] = h.w;
  }
  __syncthreads();
#pragma unroll
  for (int k = 0; k < 4; ++k) {
    int dr = rw + 16 * k;
    float f0 = bf2f(ldsT[dr][p * 4 + 0]);
    float f1 = bf2f(ldsT[dr][p * 4 + 1]);
    float f2 = bf2f(ldsT[dr][p * 4 + 2]);
    float f3 = bf2f(ldsT[dr][p * 4 + 3]);
    unsigned pk = (unsigned)__builtin_amdgcn_cvt_pk_fp8_f32(f0, f1, 0, false);
    pk = (unsigned)__builtin_amdgcn_cvt_pk_fp8_f32(f2, f3, (int)pk, true);
    *(unsigned*)(xV + ((size_t)((b * 64 + tt) * 512 + d0 + dr)) * 64 + p * 4) = pk;
  }
}

// ---------------- kernel 3: Q/K projection GEMM -> fp8 outputs ----------------
__global__ __launch_bounds__(256, 2) void proj_gemm(const unsigned short* __restrict__ A,
                                                    const unsigned short* __restrict__ wq,
                                                    const unsigned short* __restrict__ wk,
                                                    const float* __restrict__ bq,
                                                    const float* __restrict__ bk,
                                                    unsigned char* __restrict__ Qo,
                                                    unsigned char* __restrict__ Ko) {
  __shared__ unsigned short As[2][8192];
  __shared__ unsigned short Bs[2][8192];
  const int tid = threadIdx.x;
  const int mt = blockIdx.x, nt = blockIdx.y, qk = blockIdx.z;
  const unsigned short* W = qk ? wk : wq;
  const float* bias = qk ? bk : bq;
  unsigned char* out = qk ? Ko : Qo;
  const int m0 = mt * 128, n0 = nt * 128;
  const int l = tid & 63, q15 = l & 15, g = l >> 4;
  const int w = tid >> 6, wm = w >> 1, wn = w & 1;

  auto stage = [&](int buf, int k0) {
#pragma unroll
    for (int j = 0; j < 4; ++j) {
      int chunk = j * 256 + tid;
      int row = chunk >> 3, cc = chunk & 7;
      int ccs = cc ^ (row & 7);
      gload_lds16(A + (size_t)(m0 + row) * 512 + k0 + ccs * 8, &As[buf][chunk * 8]);
      gload_lds16(W + (size_t)(n0 + row) * 512 + k0 + ccs * 8, &Bs[buf][chunk * 8]);
    }
  };
  stage(0, 0);
  __syncthreads();

  f32x4 acc[4][4] = {};
  for (int kt = 0; kt < 8; ++kt) {
    int cur = kt & 1;
    if (kt < 7) stage(cur ^ 1, (kt + 1) * 64);
#pragma unroll
    for (int ks = 0; ks < 2; ++ks) {
      short8 av[4], bv[4];
#pragma unroll
      for (int mf = 0; mf < 4; ++mf) {
        int row = 64 * wm + 16 * mf + q15;
        int cb = (ks * 64 + g * 16) ^ ((row & 7) << 4);
        av[mf] = *(const short8*)((const char*)&As[cur][0] + row * 128 + cb);
      }
#pragma unroll
      for (int nf = 0; nf < 4; ++nf) {
        int row = 64 * wn + 16 * nf + q15;
        int cb = (ks * 64 + g * 16) ^ ((row & 7) << 4);
        bv[nf] = *(const short8*)((const char*)&Bs[cur][0] + row * 128 + cb);
      }
#pragma unroll
      for (int mf = 0; mf < 4; ++mf)
#pragma unroll
        for (int nf = 0; nf < 4; ++nf)
          acc[mf][nf] = __builtin_amdgcn_mfma_f32_16x16x32_bf16(av[mf], bv[nf], acc[mf][nf], 0, 0, 0);
    }
    __syncthreads();
  }
#pragma unroll
  for (int nf = 0; nf < 4; ++nf) {
    int n = n0 + 64 * wn + 16 * nf + q15;
    float bv = bias[n];
#pragma unroll
    for (int mf = 0; mf < 4; ++mf) {
      int mbase = m0 + 64 * wm + 16 * mf + 4 * g;
#pragma unroll
      for (int r = 0; r < 4; ++r)
        out[(size_t)(mbase + r) * 512 + n] = f2fp8(acc[mf][nf][r] + bv);
    }
  }
}

// ---------------- kernel 4: fused flash attention + residual (fp8, KVBLK=128) ------
// 640 threads = 10 waves:
//   waves 0-1 (QK): wave w owns q 32w..32w+31 (fp8 Q frags, 2 q-groups; each K
//                   frag read once -> 2 MFMAs). Swapped mfma_fp8(K,Q) -> S^T;
//                   per-lane online softmax; writes P(fp8,stride 136)+scale+flag.
//   waves 2-9 (PV): wave pw owns dout d 64pw..64pw+63, all 64 q; consumes
//                   P/scale of PREVIOUS tile; reg-stages next K tile with
//                   8B-granular XOR swizzle (conflict-free); V first, K second
//                   so the V vmcnt-wait leaves K loads in flight (T14).
// K LDS layout: row r (512B), 8B slot s holds K[r][8*(s ^ (r&15)) ..+8).
// All sync = __syncthreads() (one per slot).
__global__ __launch_bounds__(640, 3) void attn_kernel(const unsigned char* __restrict__ Qb,
                                                      const unsigned char* __restrict__ Kb,
                                                      const unsigned char* __restrict__ xV,
                                                      const float* __restrict__ x,
                                                      const float* __restrict__ gmp,
                                                      float* __restrict__ out) {
  extern __shared__ char smem[];
  // [0, 131072)       : Kbuf 2 x [128 rows][512 B] fp8, 8B-swizzled
  // [131072, 148480)  : P 2 x [64 q][136 B] fp8 (128 kv + 8 pad)
  // [148480, 148992)  : scale 2 x [64] f32
  // [148992, 149248)  : lsum [64] f32
  // [149248, 149264)  : flags 2 x [2] u32
  unsigned char* Pl = (unsigned char*)(smem + 131072);
  float* scale_lds = (float*)(smem + 148480);
  float* lsum_lds  = (float*)(smem + 148992);
  unsigned* flags  = (unsigned*)(smem + 149248);

  const int hw = blockIdx.x;
  const int wg = (hw & 7) * 32 + (hw >> 3);   // XCD-chunked swizzle (256 % 8 == 0)
  const int b = wg >> 6, qt = wg & 63;
  const int tid = threadIdx.x;
  const int w = tid >> 6, l = tid & 63, q15 = l & 15, g = l >> 4;
  const float qscale = 0.04419417382415922f;   // 1/sqrt(512)

  const unsigned char* KbB = Kb + (size_t)b * 4096 * 512;
  const unsigned char* xVb = xV + (size_t)b * 64 * 512 * 64;   // [tile64][d][64]

  // prologue: PV waves (tid>=128) reg-stage tile 0 into Kbuf[0]
  if (tid >= 128) {
    const int st = tid - 128, c = st & 63, w6 = st >> 6;
    long kp[16];
    const unsigned char* src = KbB + c * 8;
#pragma unroll
    for (int k = 0; k < 16; ++k)
      kp[k] = *(const long*)(src + (size_t)(8 * k + w6) * 512);
#pragma unroll
    for (int k = 0; k < 16; ++k) {
      int r = 8 * k + w6;
      *(long*)(smem + r * 512 + ((c ^ (r & 15)) << 3)) = kp[k];
    }
  }
  __syncthreads();

  if (w < 2) {
    // ================= QK + softmax waves (32 q each, 2 q-groups) =================
    long qf0[16], qf1[16];
    {
      const unsigned char* Q0 =
          Qb + ((size_t)(b * 4096 + qt * 64 + 32 * w + q15)) * 512 + g * 8;
#pragma unroll
      for (int ds = 0; ds < 16; ++ds) qf0[ds] = *(const long*)(Q0 + ds * 32);
      const unsigned char* Q1 = Q0 + 16 * 512;
#pragma unroll
      for (int ds = 0; ds < 16; ++ds) qf1[ds] = *(const long*)(Q1 + ds * 32);
    }
    float mrun0 = -1e30f, mrun1 = -1e30f, lsum0 = 0.f, lsum1 = 0.f;

#pragma unroll 1
    for (int s = 0; s <= 32; ++s) {
      if (s < 32) {
        const int cur = s & 1;
        // QK^T (swapped): S^T[kv][q], frag n covers kv 16n..16n+15 (n=0..7).
        // K read: row r=16n+q15, 8B slot (4ds+g)^q15 -> conflict-free/quarter.
        f32x4 S0[8] = {}, S1[8] = {};
        const char* kb = smem + cur * 65536;
        __builtin_amdgcn_s_setprio(1);
#pragma unroll
        for (int ds = 0; ds < 16; ++ds) {
#pragma unroll
          for (int n = 0; n < 8; ++n) {
            int r = 16 * n + q15;
            long kf = *(const long*)(kb + r * 512 + ((((ds << 2) + g) ^ q15) << 3));
            S0[n] = __builtin_amdgcn_mfma_f32_16x16x32_fp8_fp8(kf, qf0[ds], S0[n], 0, 0, 0);
            S1[n] = __builtin_amdgcn_mfma_f32_16x16x32_fp8_fp8(kf, qf1[ds], S1[n], 0, 0, 0);
          }
        }
        __builtin_amdgcn_s_setprio(0);
        // online softmax: lane owns q = 32w+16qg+q15; values kv = 16n+4g+r
        bool nochg = true;
        // ---- qg = 0 ----
        {
          float pmax = -1e30f;
#pragma unroll
          for (int n = 0; n < 8; ++n)
#pragma unroll
            for (int r = 0; r < 4; ++r) pmax = fmaxf(pmax, S0[n][r]);
          pmax = fmaxf(pmax, __shfl_xor(pmax, 16, 64));
          pmax = fmaxf(pmax, __shfl_xor(pmax, 32, 64));
          const float mnew = fmaxf(mrun0, pmax);
          nochg = nochg && (mnew == mrun0);
          const float scl = __expf((mrun0 - mnew) * qscale);
          float psum = 0.f;
          const int q_loc = 32 * w + q15;
          unsigned char* Pp = Pl + cur * 8704 + q_loc * 136 + 4 * g;
#pragma unroll
          for (int n = 0; n < 8; ++n) {
            float p0 = __expf((S0[n][0] - mnew) * qscale); psum += p0;
            float p1 = __expf((S0[n][1] - mnew) * qscale); psum += p1;
            float p2 = __expf((S0[n][2] - mnew) * qscale); psum += p2;
            float p3 = __expf((S0[n][3] - mnew) * qscale); psum += p3;
            unsigned pk = (unsigned)__builtin_amdgcn_cvt_pk_fp8_f32(p0, p1, 0, false);
            pk = (unsigned)__builtin_amdgcn_cvt_pk_fp8_f32(p2, p3, (int)pk, true);
            *(unsigned*)(Pp + 16 * n) = pk;
          }
          psum += __shfl_xor(psum, 16, 64);
          psum += __shfl_xor(psum, 32, 64);
          lsum0 = lsum0 * scl + psum;
          mrun0 = mnew;
          if (g == 0) scale_lds[cur * 64 + q_loc] = scl;
          if (s == 31 && g == 0) lsum_lds[q_loc] = lsum0;
        }
        // ---- qg = 1 ----
        {
          float pmax = -1e30f;
#pragma unroll
          for (int n = 0; n < 8; ++n)
#pragma unroll
            for (int r = 0; r < 4; ++r) pmax = fmaxf(pmax, S1[n][r]);
          pmax = fmaxf(pmax, __shfl_xor(pmax, 16, 64));
          pmax = fmaxf(pmax, __shfl_xor(pmax, 32, 64));
          const float mnew = fmaxf(mrun1, pmax);
          nochg = nochg && (mnew == mrun1);
          const float scl = __expf((mrun1 - mnew) * qscale);
          float psum = 0.f;
          const int q_loc = 32 * w + 16 + q15;
          unsigned char* Pp = Pl + cur * 8704 + q_loc * 136 + 4 * g;
#pragma unroll
          for (int n = 0; n < 8; ++n) {
            float p0 = __expf((S1[n][0] - mnew) * qscale); psum += p0;
            float p1 = __expf((S1[n][1] - mnew) * qscale); psum += p1;
            float p2 = __expf((S1[n][2] - mnew) * qscale); psum += p2;
            float p3 = __expf((S1[n][3] - mnew) * qscale); psum += p3;
            unsigned pk = (unsigned)__builtin_amdgcn_cvt_pk_fp8_f32(p0, p1, 0, false);
            pk = (unsigned)__builtin_amdgcn_cvt_pk_fp8_f32(p2, p3, (int)pk, true);
            *(unsigned*)(Pp + 16 * n) = pk;
          }
          psum += __shfl_xor(psum, 16, 64);
          psum += __shfl_xor(psum, 32, 64);
          lsum1 = lsum1 * scl + psum;
          mrun1 = mnew;
          if (g == 0) scale_lds[cur * 64 + q_loc] = scl;
          if (s == 31 && g == 0) lsum_lds[q_loc] = lsum1;
        }
        unsigned long long bal = __ballot(nochg ? 1 : 0);
        if (l == 0) flags[cur * 2 + w] = (bal == 0xFFFFFFFFFFFFFFFFull) ? 1u : 0u;
      }
      __syncthreads();
    }
  } else {
    // ================= PV + rescale + K-staging waves (64 q x 64 d each) ==========
    const int pw = w - 2;
    const int st = tid - 128, c = st & 63, w6 = st >> 6;
    f32x4 Oacc[4][4] = {};

#pragma unroll 1
    for (int s = 0; s <= 32; ++s) {
      const int tv = s - 1;            // tile consumed this slot
      const int pcur = tv & 1;
      // V frags first (older vmcnt entries -> waiting on V leaves K in flight)
      long vf[4][4];
      if (s >= 1) {
#pragma unroll
        for (int f = 0; f < 4; ++f)
#pragma unroll
          for (int ks = 0; ks < 4; ++ks)
            vf[f][ks] = *(const long*)(xVb + (size_t)(2 * tv + (ks >> 1)) * 32768
                                       + (size_t)(64 * pw + 16 * f + q15) * 64
                                       + ((ks & 1) << 5) + g * 8);
      }
      // issue next K tile loads (linear, coalesced)
      long kp[16];
      if (s < 31) {
        const unsigned char* src = KbB + (size_t)(s + 1) * 65536 + c * 8;
#pragma unroll
        for (int k = 0; k < 16; ++k)
          kp[k] = *(const long*)(src + (size_t)(8 * k + w6) * 512);
      }
      if (s >= 1) {
        uint2 fv = *(const uint2*)&flags[pcur * 2];
        const bool skip = (fv.x & fv.y) != 0;
        const float* scp = scale_lds + pcur * 64;
        const unsigned char* Pb = Pl + pcur * 8704;
#pragma unroll
        for (int qf = 0; qf < 4; ++qf) {
          const unsigned char* prow = Pb + (16 * qf + q15) * 136 + g * 8;
          long pa[4];
#pragma unroll
          for (int ks = 0; ks < 4; ++ks) pa[ks] = *(const long*)(prow + 32 * ks);
          if (!skip) {
            float s0 = scp[16 * qf + 4 * g + 0];
            float s1 = scp[16 * qf + 4 * g + 1];
            float s2 = scp[16 * qf + 4 * g + 2];
            float s3 = scp[16 * qf + 4 * g + 3];
#pragma unroll
            for (int f = 0; f < 4; ++f) {
              Oacc[qf][f][0] *= s0; Oacc[qf][f][1] *= s1;
              Oacc[qf][f][2] *= s2; Oacc[qf][f][3] *= s3;
            }
          }
          __builtin_amdgcn_s_setprio(1);
#pragma unroll
          for (int f = 0; f < 4; ++f) {
            f32x4 a = Oacc[qf][f];
#pragma unroll
            for (int ks = 0; ks < 4; ++ks)
              a = __builtin_amdgcn_mfma_f32_16x16x32_fp8_fp8(pa[ks], vf[f][ks], a, 0, 0, 0);
            Oacc[qf][f] = a;
          }
          __builtin_amdgcn_s_setprio(0);
        }
      }
      // write staged K tile (compiler inserts vmcnt wait for kp)
      if (s < 31) {
        char* dst = smem + ((s + 1) & 1) * 65536;
#pragma unroll
        for (int k = 0; k < 16; ++k) {
          int r = 8 * k + w6;
          *(long*)(dst + r * 512 + ((c ^ (r & 15)) << 3)) = kp[k];
        }
      }
      __syncthreads();
    }

    // epilogue: PV waves write out
    const float gam = gmp[0];
#pragma unroll
    for (int qf = 0; qf < 4; ++qf) {
      float li0 = 1.f / lsum_lds[16 * qf + 4 * g + 0];
      float li1 = 1.f / lsum_lds[16 * qf + 4 * g + 1];
      float li2 = 1.f / lsum_lds[16 * qf + 4 * g + 2];
      float li3 = 1.f / lsum_lds[16 * qf + 4 * g + 3];
#pragma unroll
      for (int f = 0; f < 4; ++f) {
        int d = 64 * pw + 16 * f + q15;
        size_t base = ((size_t)(b * 4096 + qt * 64 + 16 * qf + 4 * g)) * 512 + d;
        f32x4 a = Oacc[qf][f];
        out[base]        = x[base]        + gam * a[0] * li0;
        out[base + 512]  = x[base + 512]  + gam * a[1] * li1;
        out[base + 1024] = x[base + 1024] + gam * a[2] * li2;
        out[base + 1536] = x[base + 1536] + gam * a[3] * li3;
      }
    }
  }
}

// ---------------- launch ----------------
extern "C" void kernel_launch(void* const* d_in, const int* in_sizes, int n_in,
                              void* d_out, int out_size, void* d_ws, size_t ws_size,
                              hipStream_t stream) {
  (void)in_sizes; (void)n_in; (void)out_size; (void)ws_size;
  const float* x  = (const float*)d_in[0];
  const float* Wq = (const float*)d_in[1];
  const float* bq = (const float*)d_in[2];
  const float* Wk = (const float*)d_in[3];
  const float* bk = (const float*)d_in[4];
  const float* gm = (const float*)d_in[5];
  float* out = (float*)d_out;

  char* ws = (char*)d_ws;
  unsigned char*  Qb  = (unsigned char*)(ws);                 // 16384*512 fp8 = 8 MB
  unsigned char*  Kb  = (unsigned char*)(ws + 8388608);       // 8 MB
  unsigned char*  xV  = (unsigned char*)(ws + 16777216);      // 4*64*512*64 fp8 = 8 MB
  unsigned short* xb  = (unsigned short*)(ws + 25165824);     // 16384*512 bf16 = 16 MB
  unsigned short* Wqb = (unsigned short*)(ws + 41943040);     // 512*512 bf16
  unsigned short* Wkb = (unsigned short*)(ws + 42467328);     // 512*512 bf16

  hipFuncSetAttribute((const void*)attn_kernel,
                      hipFuncAttributeMaxDynamicSharedMemorySize, 149264);

  cvt_w<<<512, 256, 0, stream>>>(Wq, Wk, Wqb, Wkb);
  prep_x<<<2048, 256, 0, stream>>>(x, xb, xV);
  proj_gemm<<<dim3(128, 4, 2), 256, 0, stream>>>(xb, Wqb, Wkb, bq, bk, Qb, Kb);
  attn_kernel<<<256, 640, 149264, stream>>>(Qb, Kb, xV, x, gm, out);
}